// Round 11
// baseline (4209.290 us; speedup 1.0000x reference)
//
#include <hip/hip_runtime.h>
#include <hip/hip_bf16.h>
#include <math.h>

#define Bb 64
#define Tt 512
#define Ii 1024
#define Hh 2048
#define NBLK 128

typedef __attribute__((ext_vector_type(8))) short bf16x8;
typedef __attribute__((ext_vector_type(8))) unsigned short ushort8;
typedef __attribute__((ext_vector_type(4))) float f32x4;

__device__ __forceinline__ unsigned short f2bf(float x) {
    unsigned int u = __float_as_uint(x);
    unsigned int r = u + 0x7fffu + ((u >> 16) & 1u);
    return (unsigned short)(r >> 16);
}

// ---------------------------------------------------------------------------
__global__ __launch_bounds__(256) void cvt_kernel(
    const float* __restrict__ src, unsigned short* __restrict__ dst)
{
    const int i = (blockIdx.x * 256 + threadIdx.x) * 4;
    float4 v = *(const float4*)(src + i);
    ushort4 o;
    o.x = f2bf(v.x); o.y = f2bf(v.y); o.z = f2bf(v.z); o.w = f2bf(v.w);
    *(ushort4*)(dst + i) = o;
}

__global__ void init_flags(unsigned int* flags) {
    flags[threadIdx.x] = 0u;               // 512 per-wave flags
}

// ---------------------------------------------------------------------------
// xproj: out[M=B*T][N=H] = input[M][K=I] @ w_ih^T + b_ih   (bf16 MFMA)
// ---------------------------------------------------------------------------
__global__ __launch_bounds__(256, 2) void xproj_kernel(
    const float* __restrict__ A,
    const unsigned short* __restrict__ Wbf,
    const float* __restrict__ bias,
    float* __restrict__ out)
{
    __shared__ unsigned short As[128 * 40];
    __shared__ unsigned short Bs[128 * 40];

    const int tid  = threadIdx.x;
    const int lane = tid & 63;
    const int wid  = tid >> 6;
    const int wm   = wid & 1;
    const int wn   = wid >> 1;
    const int rlo  = lane & 15;
    const int khi  = lane >> 4;

    const int m0 = blockIdx.y * 128;
    const int n0 = blockIdx.x * 128;

    f32x4 acc[4][4];
    #pragma unroll
    for (int i = 0; i < 4; ++i)
        #pragma unroll
        for (int j = 0; j < 4; ++j) acc[i][j] = (f32x4)0.f;

    for (int k0 = 0; k0 < Ii; k0 += 32) {
        #pragma unroll
        for (int p = 0; p < 4; ++p) {
            const int flat = p * 256 + tid;
            const int row  = flat >> 3;
            const int c4   = flat & 7;
            float4 v = *(const float4*)(A + (size_t)(m0 + row) * Ii + k0 + c4 * 4);
            ushort4 o;
            o.x = f2bf(v.x); o.y = f2bf(v.y); o.z = f2bf(v.z); o.w = f2bf(v.w);
            *(ushort4*)(As + row * 40 + c4 * 4) = o;
        }
        #pragma unroll
        for (int p = 0; p < 2; ++p) {
            const int flat = p * 256 + tid;
            const int row  = flat >> 2;
            const int c8   = flat & 3;
            ushort8 v = *(const ushort8*)(Wbf + (size_t)(n0 + row) * Ii + k0 + c8 * 8);
            *(ushort8*)(Bs + row * 40 + c8 * 8) = v;
        }
        __syncthreads();

        bf16x8 af[4], bfr[4];
        #pragma unroll
        for (int i = 0; i < 4; ++i)
            af[i] = *(const bf16x8*)(As + (wm * 64 + i * 16 + rlo) * 40 + khi * 8);
        #pragma unroll
        for (int j = 0; j < 4; ++j)
            bfr[j] = *(const bf16x8*)(Bs + (wn * 64 + j * 16 + rlo) * 40 + khi * 8);
        #pragma unroll
        for (int i = 0; i < 4; ++i)
            #pragma unroll
            for (int j = 0; j < 4; ++j)
                acc[i][j] = __builtin_amdgcn_mfma_f32_16x16x32_bf16(
                    af[i], bfr[j], acc[i][j], 0, 0, 0);
        __syncthreads();
    }

    #pragma unroll
    for (int j = 0; j < 4; ++j) {
        const int col = n0 + wn * 64 + j * 16 + rlo;
        const float bj = bias[col];
        #pragma unroll
        for (int i = 0; i < 4; ++i) {
            #pragma unroll
            for (int r = 0; r < 4; ++r) {
                const int m = m0 + wm * 64 + i * 16 + khi * 4 + r;
                out[(size_t)m * Hh + col] = acc[i][j][r] + bj;
            }
        }
    }
}

// ---------------------------------------------------------------------------
// asm helpers
// ---------------------------------------------------------------------------
#define LD_FRAG(dst, base, OFF)                                               \
    asm volatile("global_load_dwordx4 %0, %1, off offset:" OFF " sc0 sc1"     \
                 : "=v"(dst) : "v"(base))

#define DRAIN16(a)                                                            \
    asm volatile("s_waitcnt vmcnt(0)"                                         \
                 : "+v"(a[0][0]), "+v"(a[0][1]), "+v"(a[0][2]), "+v"(a[0][3]),\
                   "+v"(a[0][4]), "+v"(a[0][5]), "+v"(a[0][6]), "+v"(a[0][7]),\
                   "+v"(a[1][0]), "+v"(a[1][1]), "+v"(a[1][2]), "+v"(a[1][3]),\
                   "+v"(a[1][4]), "+v"(a[1][5]), "+v"(a[1][6]), "+v"(a[1][7]) \
                 :: "memory");                                                \
    __builtin_amdgcn_sched_barrier(0)

// Raw barrier: LDS-safe (lgkm drained) but does NOT drain vmcnt.
#define RAW_BARRIER()                                                         \
    asm volatile("s_waitcnt lgkmcnt(0)\n\ts_barrier" ::: "memory")

// ---------------------------------------------------------------------------
// Persistent recurrence: 128 WGs x 512 thr (8 waves), depth-3 h ping-pong.
// WG = (rh = blk&1 -> 32 batch rows) x (cg = blk>>1 -> 32 cols).
// Wave wid = K-slice [wid*256, +256).
// Sync: per-PRODUCER-WAVE flags. Epilogue wave w of WG blk owns flag
// flags[blk*4+w] (= t+1 after its h stores drained). Consumer wave wid polls
// its 64 producer-wave flags (8 cg x 2 rh x 4 epi-waves) with one coalesced
// load + __all. No global barrier; ONE s_barrier/step for the (double-
// buffered) LDS k-split reduce. Depth-3 h buffer makes run-ahead safe.
// ---------------------------------------------------------------------------
__global__ __launch_bounds__(512)
__attribute__((amdgpu_waves_per_eu(2, 2)))
void rnn_persistent(
    const unsigned short* __restrict__ w_bf,   // [2048][2048] bf16
    unsigned short* __restrict__ h_bf,         // [3][64][2048] bf16 ring
    const float* __restrict__ b_hh,            // [2048]
    const float* __restrict__ internal,        // [64][512]
    float* __restrict__ out,                   // [B][T][H] ++ [B][H]
    unsigned int* __restrict__ flags)          // [128*4] per-wave flags
{
    __shared__ f32x4 red4[2][8 * 256];         // 64 KiB double-buffered

    const int tid  = threadIdx.x;
    const int lane = tid & 63;
    const int wid  = tid >> 6;                 // K-slice 0..7
    const int rlo  = lane & 15;
    const int khi  = lane >> 4;
    const int blk  = blockIdx.x;
    const int rh   = blk & 1;                  // rows rh*32..+31
    const int cg   = blk >> 1;                 // cols cg*32..+31

    // ---- preload w_hh slice into registers (stationary for all 512 steps)
    bf16x8 wf[2][8];
    #pragma unroll
    for (int nt = 0; nt < 2; ++nt) {
        const unsigned short* wrow =
            w_bf + (size_t)(cg * 32 + nt * 16 + rlo) * Hh + wid * 256 + khi * 8;
        #pragma unroll
        for (int kit = 0; kit < 8; ++kit)
            wf[nt][kit] = *(const bf16x8*)(wrow + kit * 32);
    }

    // ---- producer-flag index this wave polls: lane -> (cg', rh', w')
    const int pcg  = wid * 8 + (lane & 7);
    const int prh  = (lane >> 3) & 1;
    const int pw   = (lane >> 4) & 3;
    const int fidx = ((pcg * 2 + prh) << 2) + pw;

    // ---- epilogue decode (r9/r10 verified)
    const int em    = (tid >> 6) & 1;
    const int ent   = (tid >> 7) & 1;          // valid for tid<256
    const int odd   = lane & 1;
    const int clloc = (ent * 16 + rlo) & ~1;
    const int cl    = cg * 32 + clloc;         // even col of the pair
    const int rAl   = em * 16 + khi * 4 + 2 * odd;
    const int rAg   = rh * 32 + rAl;
    const int rBg   = rAg + 1;
    const float2 bh2 = (tid < 256) ? *(const float2*)(b_hh + cl)
                                   : make_float2(0.f, 0.f);

    float2 xpA = make_float2(0.f, 0.f), xpB = make_float2(0.f, 0.f);
    float  nzA = 0.f, nzB = 0.f;
    if (tid < 256) {
        xpA = *(const float2*)(out + ((size_t)rAg * Tt + 0) * Hh + cl);
        xpB = *(const float2*)(out + ((size_t)rBg * Tt + 0) * Hh + cl);
        nzA = internal[rAg * Tt + 0];
        nzB = internal[rBg * Tt + 0];
    }
    float2 gA_d = make_float2(0.f, 0.f), gB_d = make_float2(0.f, 0.f);

    for (int t = 0; t < Tt; ++t) {
        const bool last = (t == Tt - 1);
        const unsigned short* h_cur = h_bf + (size_t)(t % 3) * Bb * Hh;
        unsigned short*       h_nxt = h_bf + (size_t)((t + 1) % 3) * Bb * Hh;

        // ---- poll: my 64 producer waves must have written h_t
        {
            const unsigned int tgt = (unsigned int)t;
            while (true) {
                unsigned int f = __hip_atomic_load(
                    flags + fidx, __ATOMIC_RELAXED, __HIP_MEMORY_SCOPE_AGENT);
                if (__all(f >= tgt)) break;
                __builtin_amdgcn_s_sleep(1);
            }
        }

        // ---- issue h loads (16 frags, one drain)
        const unsigned short* am0 =
            h_cur + (size_t)(rh * 32 + rlo) * Hh + wid * 256 + khi * 8;
        const unsigned short* am1 = am0 + (size_t)16 * Hh;

        bf16x8 a[2][8];
        LD_FRAG(a[0][0], am0, "0");   LD_FRAG(a[0][1], am0, "64");
        LD_FRAG(a[0][2], am0, "128"); LD_FRAG(a[0][3], am0, "192");
        LD_FRAG(a[0][4], am0, "256"); LD_FRAG(a[0][5], am0, "320");
        LD_FRAG(a[0][6], am0, "384"); LD_FRAG(a[0][7], am0, "448");
        LD_FRAG(a[1][0], am1, "0");   LD_FRAG(a[1][1], am1, "64");
        LD_FRAG(a[1][2], am1, "128"); LD_FRAG(a[1][3], am1, "192");
        LD_FRAG(a[1][4], am1, "256"); LD_FRAG(a[1][5], am1, "320");
        LD_FRAG(a[1][6], am1, "384"); LD_FRAG(a[1][7], am1, "448");

        // ---- deferred out[t-1] stores ride the drain
        if (tid < 256 && t > 0) {
            *(float2*)(out + ((size_t)rAg * Tt + (t - 1)) * Hh + cl) = gA_d;
            *(float2*)(out + ((size_t)rBg * Tt + (t - 1)) * Hh + cl) = gB_d;
        }

        DRAIN16(a);

        // ---- MFMA: 2 mtiles x 2 ntiles x 8 kits
        f32x4 acc[2][2];
        #pragma unroll
        for (int m = 0; m < 2; ++m)
            #pragma unroll
            for (int nt = 0; nt < 2; ++nt) acc[m][nt] = (f32x4)0.f;
        #pragma unroll
        for (int kk = 0; kk < 8; ++kk)
            #pragma unroll
            for (int m = 0; m < 2; ++m)
                #pragma unroll
                for (int nt = 0; nt < 2; ++nt)
                    acc[m][nt] = __builtin_amdgcn_mfma_f32_16x16x32_bf16(
                        a[m][kk], wf[nt][kk], acc[m][nt], 0, 0, 0);

        // ---- k-split reduce into double-buffered LDS; ONE barrier per step
        f32x4* rb = red4[t & 1];
        #pragma unroll
        for (int nt = 0; nt < 2; ++nt)
            #pragma unroll
            for (int m = 0; m < 2; ++m)
                rb[wid * 256 + (nt * 2 + m) * 64 + lane] = acc[m][nt];
        RAW_BARRIER();

        // ---- epilogue: waves 0-3 only; waves 4-7 run ahead to next poll
        if (tid < 256) {
            f32x4 s4 = (f32x4)0.f;
            #pragma unroll
            for (int ks = 0; ks < 8; ++ks)
                s4 += rb[ks * 256 + tid];

            f32x4 o4;
            #pragma unroll
            for (int i = 0; i < 4; ++i)
                o4[i] = __shfl_xor(s4[i], 1, 64);

            const float sA_lo = odd ? o4[2] : s4[0];
            const float sA_hi = odd ? s4[2] : o4[0];
            const float sB_lo = odd ? o4[3] : s4[1];
            const float sB_hi = odd ? s4[3] : o4[1];

            float2 gA, gB;
            gA.x = tanhf(xpA.x + nzA + bh2.x + sA_lo);
            gA.y = tanhf(xpA.y + nzA + bh2.y + sA_hi);
            gB.x = tanhf(xpB.x + nzB + bh2.x + sB_lo);
            gB.y = tanhf(xpB.y + nzB + bh2.y + sB_hi);

            const unsigned int hpA =
                (unsigned int)f2bf(gA.x) | ((unsigned int)f2bf(gA.y) << 16);
            const unsigned int hpB =
                (unsigned int)f2bf(gB.x) | ((unsigned int)f2bf(gB.y) << 16);
            __hip_atomic_store((unsigned int*)h_nxt + ((size_t)rAg * Hh + cl) / 2,
                               hpA, __ATOMIC_RELAXED, __HIP_MEMORY_SCOPE_AGENT);
            __hip_atomic_store((unsigned int*)h_nxt + ((size_t)rBg * Hh + cl) / 2,
                               hpB, __ATOMIC_RELAXED, __HIP_MEMORY_SCOPE_AGENT);

            if (last) {
                *(float2*)(out + ((size_t)rAg * Tt + t) * Hh + cl) = gA;
                *(float2*)(out + ((size_t)rBg * Tt + t) * Hh + cl) = gB;
                float* tail = out + (size_t)Bb * Tt * Hh;
                *(float2*)(tail + (size_t)rAg * Hh + cl) = gA;
                *(float2*)(tail + (size_t)rBg * Hh + cl) = gB;
            } else {
                gA_d = gA; gB_d = gB;

                // per-WAVE drain of own h stores, then own flag (no barrier)
                asm volatile("s_waitcnt vmcnt(0)" ::: "memory");
                if (lane == 0)
                    __hip_atomic_store(flags + blk * 4 + wid,
                                       (unsigned int)(t + 1),
                                       __ATOMIC_RELAXED, __HIP_MEMORY_SCOPE_AGENT);

                // xp/nz prefetch for t+1 rides the next poll/drain
                xpA = *(const float2*)(out + ((size_t)rAg * Tt + t + 1) * Hh + cl);
                xpB = *(const float2*)(out + ((size_t)rBg * Tt + t + 1) * Hh + cl);
                nzA = internal[rAg * Tt + t + 1];
                nzB = internal[rBg * Tt + t + 1];
            }
        }
    }
}

// ---------------------------------------------------------------------------
extern "C" void kernel_launch(void* const* d_in, const int* in_sizes, int n_in,
                              void* d_out, int out_size, void* d_ws, size_t ws_size,
                              hipStream_t stream) {
    const float* input    = (const float*)d_in[0];
    const float* internal = (const float*)d_in[1];
    const float* w_ih     = (const float*)d_in[2];
    const float* w_hh     = (const float*)d_in[3];
    const float* b_ih     = (const float*)d_in[4];
    const float* b_hh     = (const float*)d_in[5];
    const float* h0       = (const float*)d_in[6];
    float* out = (float*)d_out;

    // ws: w_hh_bf [4M us] | w_ih_bf [2M us] | h_bf[3][64][2048] | flags[512]
    unsigned short* w_hh_bf = (unsigned short*)d_ws;
    unsigned short* w_ih_bf = w_hh_bf + (size_t)Hh * Hh;
    unsigned short* h_bf    = w_ih_bf + (size_t)Hh * Ii;
    unsigned int*   flags   = (unsigned int*)(h_bf + (size_t)3 * Bb * Hh);

    hipLaunchKernelGGL(init_flags, dim3(1), dim3(512), 0, stream, flags);
    hipLaunchKernelGGL(cvt_kernel, dim3((Hh * Hh) / 1024), dim3(256), 0, stream,
                       w_hh, w_hh_bf);
    hipLaunchKernelGGL(cvt_kernel, dim3((Hh * Ii) / 1024), dim3(256), 0, stream,
                       w_ih, w_ih_bf);
    hipLaunchKernelGGL(cvt_kernel, dim3((Bb * Hh) / 1024), dim3(256), 0, stream,
                       h0, h_bf);

    dim3 g1(Hh / 128, (Bb * Tt) / 128);
    hipLaunchKernelGGL(xproj_kernel, g1, dim3(256), 0, stream,
                       input, w_ih_bf, b_ih, out);

    void* args[] = {(void*)&w_hh_bf, (void*)&h_bf, (void*)&b_hh,
                    (void*)&internal, (void*)&out, (void*)&flags};
    hipLaunchCooperativeKernel((void*)rnn_persistent, dim3(NBLK), dim3(512),
                               args, 0, stream);
}

// Round 13
// 3957.084 us; speedup vs baseline: 1.0637x; 1.0637x over previous
//
#include <hip/hip_runtime.h>
#include <hip/hip_bf16.h>
#include <math.h>

#define Bb 64
#define Tt 512
#define Ii 1024
#define Hh 2048
#define NBLK 128

typedef __attribute__((ext_vector_type(8))) short bf16x8;
typedef __attribute__((ext_vector_type(8))) unsigned short ushort8;
typedef __attribute__((ext_vector_type(4))) float f32x4;

__device__ __forceinline__ unsigned short f2bf(float x) {
    unsigned int u = __float_as_uint(x);
    unsigned int r = u + 0x7fffu + ((u >> 16) & 1u);
    return (unsigned short)(r >> 16);
}

// ---------------------------------------------------------------------------
__global__ __launch_bounds__(256) void cvt_kernel(
    const float* __restrict__ src, unsigned short* __restrict__ dst)
{
    const int i = (blockIdx.x * 256 + threadIdx.x) * 4;
    float4 v = *(const float4*)(src + i);
    ushort4 o;
    o.x = f2bf(v.x); o.y = f2bf(v.y); o.z = f2bf(v.z); o.w = f2bf(v.w);
    *(ushort4*)(dst + i) = o;
}

__global__ void init_flags(unsigned int* flags) {
    if (threadIdx.x < NBLK + 2) flags[threadIdx.x] = 0u;   // 128 flags + 2 roots
}

// ---------------------------------------------------------------------------
// xproj: out[M=B*T][N=H] = input[M][K=I] @ w_ih^T + b_ih   (bf16 MFMA)
// ---------------------------------------------------------------------------
__global__ __launch_bounds__(256, 2) void xproj_kernel(
    const float* __restrict__ A,
    const unsigned short* __restrict__ Wbf,
    const float* __restrict__ bias,
    float* __restrict__ out)
{
    __shared__ unsigned short As[128 * 40];
    __shared__ unsigned short Bs[128 * 40];

    const int tid  = threadIdx.x;
    const int lane = tid & 63;
    const int wid  = tid >> 6;
    const int wm   = wid & 1;
    const int wn   = wid >> 1;
    const int rlo  = lane & 15;
    const int khi  = lane >> 4;

    const int m0 = blockIdx.y * 128;
    const int n0 = blockIdx.x * 128;

    f32x4 acc[4][4];
    #pragma unroll
    for (int i = 0; i < 4; ++i)
        #pragma unroll
        for (int j = 0; j < 4; ++j) acc[i][j] = (f32x4)0.f;

    for (int k0 = 0; k0 < Ii; k0 += 32) {
        #pragma unroll
        for (int p = 0; p < 4; ++p) {
            const int flat = p * 256 + tid;
            const int row  = flat >> 3;
            const int c4   = flat & 7;
            float4 v = *(const float4*)(A + (size_t)(m0 + row) * Ii + k0 + c4 * 4);
            ushort4 o;
            o.x = f2bf(v.x); o.y = f2bf(v.y); o.z = f2bf(v.z); o.w = f2bf(v.w);
            *(ushort4*)(As + row * 40 + c4 * 4) = o;
        }
        #pragma unroll
        for (int p = 0; p < 2; ++p) {
            const int flat = p * 256 + tid;
            const int row  = flat >> 2;
            const int c8   = flat & 3;
            ushort8 v = *(const ushort8*)(Wbf + (size_t)(n0 + row) * Ii + k0 + c8 * 8);
            *(ushort8*)(Bs + row * 40 + c8 * 8) = v;
        }
        __syncthreads();

        bf16x8 af[4], bfr[4];
        #pragma unroll
        for (int i = 0; i < 4; ++i)
            af[i] = *(const bf16x8*)(As + (wm * 64 + i * 16 + rlo) * 40 + khi * 8);
        #pragma unroll
        for (int j = 0; j < 4; ++j)
            bfr[j] = *(const bf16x8*)(Bs + (wn * 64 + j * 16 + rlo) * 40 + khi * 8);
        #pragma unroll
        for (int i = 0; i < 4; ++i)
            #pragma unroll
            for (int j = 0; j < 4; ++j)
                acc[i][j] = __builtin_amdgcn_mfma_f32_16x16x32_bf16(
                    af[i], bfr[j], acc[i][j], 0, 0, 0);
        __syncthreads();
    }

    #pragma unroll
    for (int j = 0; j < 4; ++j) {
        const int col = n0 + wn * 64 + j * 16 + rlo;
        const float bj = bias[col];
        #pragma unroll
        for (int i = 0; i < 4; ++i) {
            #pragma unroll
            for (int r = 0; r < 4; ++r) {
                const int m = m0 + wm * 64 + i * 16 + khi * 4 + r;
                out[(size_t)m * Hh + col] = acc[i][j][r] + bj;
            }
        }
    }
}

// ---------------------------------------------------------------------------
// asm helpers
// ---------------------------------------------------------------------------
#define LD_FRAG(dst, base, OFF)                                               \
    asm volatile("global_load_dwordx4 %0, %1, off offset:" OFF " sc0 sc1"     \
                 : "=v"(dst) : "v"(base))

// plain cached 16B load (w preload; L2 path is fine for read-only w)
#define LD_FRAG_C(dst, base, OFF)                                             \
    asm volatile("global_load_dwordx4 %0, %1, off offset:" OFF                \
                 : "=v"(dst) : "v"(base))

#define DRAIN16(a)                                                            \
    asm volatile("s_waitcnt vmcnt(0)"                                         \
                 : "+v"(a[0][0]), "+v"(a[0][1]), "+v"(a[0][2]), "+v"(a[0][3]),\
                   "+v"(a[0][4]), "+v"(a[0][5]), "+v"(a[0][6]), "+v"(a[0][7]),\
                   "+v"(a[1][0]), "+v"(a[1][1]), "+v"(a[1][2]), "+v"(a[1][3]),\
                   "+v"(a[1][4]), "+v"(a[1][5]), "+v"(a[1][6]), "+v"(a[1][7]) \
                 :: "memory");                                                \
    __builtin_amdgcn_sched_barrier(0)

// Raw barrier: LDS-safe (lgkm drained) but does NOT drain vmcnt.
#define RAW_BARRIER()                                                         \
    asm volatile("s_waitcnt lgkmcnt(0)\n\ts_barrier" ::: "memory")

// ---------------------------------------------------------------------------
// Persistent recurrence: 128 WGs x 512 thr (8 waves).
// WG = (rh = blk&1 -> 32 batch rows) x (cg = blk>>1 -> 32 cols).
// Wave wid = K-slice [wid*256, +256). Per wave: 16 frags, ONE drain, 32 MFMA.
// w_hh slice PINNED in VGPRs via inline-asm loads (compiler cannot remat).
// Sync: the two rh-halves are independent domains; each has 64 flags, its
// own aggregator WG (blk 0 / blk 1, wave 7) and its own root flag.
// ---------------------------------------------------------------------------
__global__ __launch_bounds__(512, 2) void rnn_persistent(
    const unsigned short* __restrict__ w_bf,   // [2048][2048] bf16
    unsigned short* __restrict__ h_bf,         // [2][64][2048] bf16 ping-pong
    const float* __restrict__ b_hh,            // [2048]
    const float* __restrict__ internal,        // [64][512]
    float* __restrict__ out,                   // [B][T][H] ++ [B][H]
    unsigned int* __restrict__ flags)          // [NBLK] flags + [2] roots
{
    __shared__ f32x4 red4[8 * 256];            // 32 KiB

    const int tid  = threadIdx.x;
    const int lane = tid & 63;
    const int wid  = tid >> 6;                 // K-slice 0..7
    const int rlo  = lane & 15;
    const int khi  = lane >> 4;
    const int blk  = blockIdx.x;
    const int rh   = blk & 1;                  // rows rh*32..+31
    const int cg   = blk >> 1;                 // cols cg*32..+31

    // ---- preload w_hh slice, PINNED via asm (no remat into the loop)
    bf16x8 wf[2][8];
    {
        const unsigned short* w0 =
            w_bf + (size_t)(cg * 32 + rlo) * Hh + wid * 256 + khi * 8;
        const unsigned short* w1 = w0 + (size_t)16 * Hh;
        LD_FRAG_C(wf[0][0], w0, "0");   LD_FRAG_C(wf[0][1], w0, "64");
        LD_FRAG_C(wf[0][2], w0, "128"); LD_FRAG_C(wf[0][3], w0, "192");
        LD_FRAG_C(wf[0][4], w0, "256"); LD_FRAG_C(wf[0][5], w0, "320");
        LD_FRAG_C(wf[0][6], w0, "384"); LD_FRAG_C(wf[0][7], w0, "448");
        LD_FRAG_C(wf[1][0], w1, "0");   LD_FRAG_C(wf[1][1], w1, "64");
        LD_FRAG_C(wf[1][2], w1, "128"); LD_FRAG_C(wf[1][3], w1, "192");
        LD_FRAG_C(wf[1][4], w1, "256"); LD_FRAG_C(wf[1][5], w1, "320");
        LD_FRAG_C(wf[1][6], w1, "384"); LD_FRAG_C(wf[1][7], w1, "448");
        DRAIN16(wf);
    }

    // ---- epilogue decode (r9/r10 verified)
    const int em    = (tid >> 6) & 1;
    const int ent   = (tid >> 7) & 1;          // valid for tid<256
    const int odd   = lane & 1;
    const int clloc = (ent * 16 + rlo) & ~1;
    const int cl    = cg * 32 + clloc;         // even col of the pair
    const int rAl   = em * 16 + khi * 4 + 2 * odd;
    const int rAg   = rh * 32 + rAl;           // global batch row A
    const int rBg   = rAg + 1;                 // global batch row B
    const float2 bh2 = (tid < 256) ? *(const float2*)(b_hh + cl)
                                   : make_float2(0.f, 0.f);

    float2 xpA = make_float2(0.f, 0.f), xpB = make_float2(0.f, 0.f);
    float  nzA = 0.f, nzB = 0.f;
    if (tid < 256) {
        xpA = *(const float2*)(out + ((size_t)rAg * Tt + 0) * Hh + cl);
        xpB = *(const float2*)(out + ((size_t)rBg * Tt + 0) * Hh + cl);
        nzA = internal[rAg * Tt + 0];
        nzB = internal[rBg * Tt + 0];
    }
    float2 gA_d = make_float2(0.f, 0.f), gB_d = make_float2(0.f, 0.f);

    for (int t = 0; t < Tt; ++t) {
        const bool last = (t == Tt - 1);
        const unsigned short* h_cur = h_bf + (size_t)(t & 1) * Bb * Hh;
        unsigned short*       h_nxt = h_bf + (size_t)((t + 1) & 1) * Bb * Hh;

        // ---- (a) issue h-fragment loads first (longest latency)
        const unsigned short* am0 =
            h_cur + (size_t)(rh * 32 + rlo) * Hh + wid * 256 + khi * 8;
        const unsigned short* am1 = am0 + (size_t)16 * Hh;

        bf16x8 a[2][8];
        LD_FRAG(a[0][0], am0, "0");   LD_FRAG(a[0][1], am0, "64");
        LD_FRAG(a[0][2], am0, "128"); LD_FRAG(a[0][3], am0, "192");
        LD_FRAG(a[0][4], am0, "256"); LD_FRAG(a[0][5], am0, "320");
        LD_FRAG(a[0][6], am0, "384"); LD_FRAG(a[0][7], am0, "448");
        LD_FRAG(a[1][0], am1, "0");   LD_FRAG(a[1][1], am1, "64");
        LD_FRAG(a[1][2], am1, "128"); LD_FRAG(a[1][3], am1, "192");
        LD_FRAG(a[1][4], am1, "256"); LD_FRAG(a[1][5], am1, "320");
        LD_FRAG(a[1][6], am1, "384"); LD_FRAG(a[1][7], am1, "448");

        // ---- (b) deferred out[t-1] stores ride the same drain
        if (tid < 256 && t > 0) {
            *(float2*)(out + ((size_t)rAg * Tt + (t - 1)) * Hh + cl) = gA_d;
            *(float2*)(out + ((size_t)rBg * Tt + (t - 1)) * Hh + cl) = gB_d;
        }

        // ---- (d) single drain releases everything (incl. xp prefetches)
        DRAIN16(a);

        // ---- (e) MFMA: 2 mtiles x 2 ntiles x 8 kits
        f32x4 acc[2][2];
        #pragma unroll
        for (int m = 0; m < 2; ++m)
            #pragma unroll
            for (int nt = 0; nt < 2; ++nt) acc[m][nt] = (f32x4)0.f;
        #pragma unroll
        for (int kk = 0; kk < 8; ++kk)
            #pragma unroll
            for (int m = 0; m < 2; ++m)
                #pragma unroll
                for (int nt = 0; nt < 2; ++nt)
                    acc[m][nt] = __builtin_amdgcn_mfma_f32_16x16x32_bf16(
                        a[m][kk], wf[nt][kk], acc[m][nt], 0, 0, 0);

        // ---- (f) 8-way k-split reduce (raw barrier: LDS only)
        #pragma unroll
        for (int nt = 0; nt < 2; ++nt)
            #pragma unroll
            for (int m = 0; m < 2; ++m)
                red4[wid * 256 + (nt * 2 + m) * 64 + lane] = acc[m][nt];
        RAW_BARRIER();

        // ---- (g) epilogue: waves 0-3
        if (tid < 256) {
            f32x4 s4 = (f32x4)0.f;
            #pragma unroll
            for (int ks = 0; ks < 8; ++ks)
                s4 += red4[ks * 256 + tid];

            f32x4 o4;
            #pragma unroll
            for (int i = 0; i < 4; ++i)
                o4[i] = __shfl_xor(s4[i], 1, 64);

            const float sA_lo = odd ? o4[2] : s4[0];
            const float sA_hi = odd ? s4[2] : o4[0];
            const float sB_lo = odd ? o4[3] : s4[1];
            const float sB_hi = odd ? s4[3] : o4[1];

            float2 gA, gB;
            gA.x = tanhf(xpA.x + nzA + bh2.x + sA_lo);
            gA.y = tanhf(xpA.y + nzA + bh2.y + sA_hi);
            gB.x = tanhf(xpB.x + nzB + bh2.x + sB_lo);
            gB.y = tanhf(xpB.y + nzB + bh2.y + sB_hi);

            const unsigned int hpA =
                (unsigned int)f2bf(gA.x) | ((unsigned int)f2bf(gA.y) << 16);
            const unsigned int hpB =
                (unsigned int)f2bf(gB.x) | ((unsigned int)f2bf(gB.y) << 16);
            __hip_atomic_store((unsigned int*)h_nxt + ((size_t)rAg * Hh + cl) / 2,
                               hpA, __ATOMIC_RELAXED, __HIP_MEMORY_SCOPE_AGENT);
            __hip_atomic_store((unsigned int*)h_nxt + ((size_t)rBg * Hh + cl) / 2,
                               hpB, __ATOMIC_RELAXED, __HIP_MEMORY_SCOPE_AGENT);

            if (last) {
                *(float2*)(out + ((size_t)rAg * Tt + t) * Hh + cl) = gA;
                *(float2*)(out + ((size_t)rBg * Tt + t) * Hh + cl) = gB;
                float* tail = out + (size_t)Bb * Tt * Hh;
                *(float2*)(tail + (size_t)rAg * Hh + cl) = gA;
                *(float2*)(tail + (size_t)rBg * Hh + cl) = gB;
            } else {
                gA_d = gA; gB_d = gB;      // defer to next iteration
            }
        }
        if (last) break;

        // ---- (i) per-wave drain of h stores (only h outstanding here)
        asm volatile("s_waitcnt vmcnt(0)" ::: "memory");

        // ---- xp/nz prefetch for t+1: rides the barrier wait, drained by
        //      next step's DRAIN16.
        if (tid < 256) {
            xpA = *(const float2*)(out + ((size_t)rAg * Tt + t + 1) * Hh + cl);
            xpB = *(const float2*)(out + ((size_t)rBg * Tt + t + 1) * Hh + cl);
            nzA = internal[rAg * Tt + t + 1];
            nzB = internal[rBg * Tt + t + 1];
        }

        RAW_BARRIER();                     // all waves' h stores drained

        // ---- arrive: one flag store per WG
        if (tid == 0)
            __hip_atomic_store(flags + blk, (unsigned int)(t + 1),
                               __ATOMIC_RELAXED, __HIP_MEMORY_SCOPE_AGENT);

        // ---- tree barrier, split by independent rh-half domains
        const unsigned int tgt = (unsigned int)(t + 1);
        if (blk < 2 && wid == 7) {
            // aggregator for half `blk`: polls the 64 flags of its half
            while (true) {
                unsigned int f = __hip_atomic_load(
                    flags + lane * 2 + blk, __ATOMIC_RELAXED,
                    __HIP_MEMORY_SCOPE_AGENT);
                if (__all(f >= tgt)) break;
                __builtin_amdgcn_s_sleep(1);
            }
            if (lane == 0)
                __hip_atomic_store(flags + NBLK + blk, tgt, __ATOMIC_RELAXED,
                                   __HIP_MEMORY_SCOPE_AGENT);
        } else if (wid == 7) {
            // everyone else: poll their half's root flag
            while (__hip_atomic_load(flags + NBLK + rh, __ATOMIC_RELAXED,
                                     __HIP_MEMORY_SCOPE_AGENT) < tgt)
                __builtin_amdgcn_s_sleep(1);
        }
        RAW_BARRIER();                     // release: root seen by wave 7
    }
}

// ---------------------------------------------------------------------------
extern "C" void kernel_launch(void* const* d_in, const int* in_sizes, int n_in,
                              void* d_out, int out_size, void* d_ws, size_t ws_size,
                              hipStream_t stream) {
    const float* input    = (const float*)d_in[0];
    const float* internal = (const float*)d_in[1];
    const float* w_ih     = (const float*)d_in[2];
    const float* w_hh     = (const float*)d_in[3];
    const float* b_ih     = (const float*)d_in[4];
    const float* b_hh     = (const float*)d_in[5];
    const float* h0       = (const float*)d_in[6];
    float* out = (float*)d_out;

    // ws: w_hh_bf [4M us] | w_ih_bf [2M us] | h_bf[2][64][2048] | flags[130]
    unsigned short* w_hh_bf = (unsigned short*)d_ws;
    unsigned short* w_ih_bf = w_hh_bf + (size_t)Hh * Hh;
    unsigned short* h_bf    = w_ih_bf + (size_t)Hh * Ii;
    unsigned int*   flags   = (unsigned int*)(h_bf + (size_t)2 * Bb * Hh);

    hipLaunchKernelGGL(init_flags, dim3(1), dim3(256), 0, stream, flags);
    hipLaunchKernelGGL(cvt_kernel, dim3((Hh * Hh) / 1024), dim3(256), 0, stream,
                       w_hh, w_hh_bf);
    hipLaunchKernelGGL(cvt_kernel, dim3((Hh * Ii) / 1024), dim3(256), 0, stream,
                       w_ih, w_ih_bf);
    hipLaunchKernelGGL(cvt_kernel, dim3((Bb * Hh) / 1024), dim3(256), 0, stream,
                       h0, h_bf);

    dim3 g1(Hh / 128, (Bb * Tt) / 128);
    hipLaunchKernelGGL(xproj_kernel, g1, dim3(256), 0, stream,
                       input, w_ih_bf, b_ih, out);

    void* args[] = {(void*)&w_hh_bf, (void*)&h_bf, (void*)&b_hh,
                    (void*)&internal, (void*)&out, (void*)&flags};
    hipLaunchCooperativeKernel((void*)rnn_persistent, dim3(NBLK), dim3(512),
                               args, 0, stream);
}

// Round 14
// 3808.514 us; speedup vs baseline: 1.1052x; 1.0390x over previous
//
#include <hip/hip_runtime.h>
#include <hip/hip_bf16.h>
#include <math.h>

#define Bb 64
#define Tt 512
#define Ii 1024
#define Hh 2048
#define NBLK 128

typedef __attribute__((ext_vector_type(8))) short bf16x8;
typedef __attribute__((ext_vector_type(8))) unsigned short ushort8;
typedef __attribute__((ext_vector_type(4))) float f32x4;

__device__ __forceinline__ unsigned short f2bf(float x) {
    unsigned int u = __float_as_uint(x);
    unsigned int r = u + 0x7fffu + ((u >> 16) & 1u);
    return (unsigned short)(r >> 16);
}

// ---------------------------------------------------------------------------
__global__ __launch_bounds__(256) void cvt_kernel(
    const float* __restrict__ src, unsigned short* __restrict__ dst)
{
    const int i = (blockIdx.x * 256 + threadIdx.x) * 4;
    float4 v = *(const float4*)(src + i);
    ushort4 o;
    o.x = f2bf(v.x); o.y = f2bf(v.y); o.z = f2bf(v.z); o.w = f2bf(v.w);
    *(ushort4*)(dst + i) = o;
}

// flags: [512] per-epi-wave arrivals | [512] replicated roots (2 halves x 16
// copies x 16-dword stride)
__global__ __launch_bounds__(1024) void init_flags(unsigned int* flags) {
    flags[threadIdx.x] = 0u;
}

// ---------------------------------------------------------------------------
// xproj: out[M=B*T][N=H] = input[M][K=I] @ w_ih^T + b_ih   (bf16 MFMA)
// ---------------------------------------------------------------------------
__global__ __launch_bounds__(256, 2) void xproj_kernel(
    const float* __restrict__ A,
    const unsigned short* __restrict__ Wbf,
    const float* __restrict__ bias,
    float* __restrict__ out)
{
    __shared__ unsigned short As[128 * 40];
    __shared__ unsigned short Bs[128 * 40];

    const int tid  = threadIdx.x;
    const int lane = tid & 63;
    const int wid  = tid >> 6;
    const int wm   = wid & 1;
    const int wn   = wid >> 1;
    const int rlo  = lane & 15;
    const int khi  = lane >> 4;

    const int m0 = blockIdx.y * 128;
    const int n0 = blockIdx.x * 128;

    f32x4 acc[4][4];
    #pragma unroll
    for (int i = 0; i < 4; ++i)
        #pragma unroll
        for (int j = 0; j < 4; ++j) acc[i][j] = (f32x4)0.f;

    for (int k0 = 0; k0 < Ii; k0 += 32) {
        #pragma unroll
        for (int p = 0; p < 4; ++p) {
            const int flat = p * 256 + tid;
            const int row  = flat >> 3;
            const int c4   = flat & 7;
            float4 v = *(const float4*)(A + (size_t)(m0 + row) * Ii + k0 + c4 * 4);
            ushort4 o;
            o.x = f2bf(v.x); o.y = f2bf(v.y); o.z = f2bf(v.z); o.w = f2bf(v.w);
            *(ushort4*)(As + row * 40 + c4 * 4) = o;
        }
        #pragma unroll
        for (int p = 0; p < 2; ++p) {
            const int flat = p * 256 + tid;
            const int row  = flat >> 2;
            const int c8   = flat & 3;
            ushort8 v = *(const ushort8*)(Wbf + (size_t)(n0 + row) * Ii + k0 + c8 * 8);
            *(ushort8*)(Bs + row * 40 + c8 * 8) = v;
        }
        __syncthreads();

        bf16x8 af[4], bfr[4];
        #pragma unroll
        for (int i = 0; i < 4; ++i)
            af[i] = *(const bf16x8*)(As + (wm * 64 + i * 16 + rlo) * 40 + khi * 8);
        #pragma unroll
        for (int j = 0; j < 4; ++j)
            bfr[j] = *(const bf16x8*)(Bs + (wn * 64 + j * 16 + rlo) * 40 + khi * 8);
        #pragma unroll
        for (int i = 0; i < 4; ++i)
            #pragma unroll
            for (int j = 0; j < 4; ++j)
                acc[i][j] = __builtin_amdgcn_mfma_f32_16x16x32_bf16(
                    af[i], bfr[j], acc[i][j], 0, 0, 0);
        __syncthreads();
    }

    #pragma unroll
    for (int j = 0; j < 4; ++j) {
        const int col = n0 + wn * 64 + j * 16 + rlo;
        const float bj = bias[col];
        #pragma unroll
        for (int i = 0; i < 4; ++i) {
            #pragma unroll
            for (int r = 0; r < 4; ++r) {
                const int m = m0 + wm * 64 + i * 16 + khi * 4 + r;
                out[(size_t)m * Hh + col] = acc[i][j][r] + bj;
            }
        }
    }
}

// ---------------------------------------------------------------------------
// asm helpers
// ---------------------------------------------------------------------------
#define LD_FRAG(dst, base, OFF)                                               \
    asm volatile("global_load_dwordx4 %0, %1, off offset:" OFF " sc0 sc1"     \
                 : "=v"(dst) : "v"(base))

#define LD_FRAG_C(dst, base, OFF)                                             \
    asm volatile("global_load_dwordx4 %0, %1, off offset:" OFF                \
                 : "=v"(dst) : "v"(base))

#define DRAIN16(a)                                                            \
    asm volatile("s_waitcnt vmcnt(0)"                                         \
                 : "+v"(a[0][0]), "+v"(a[0][1]), "+v"(a[0][2]), "+v"(a[0][3]),\
                   "+v"(a[0][4]), "+v"(a[0][5]), "+v"(a[0][6]), "+v"(a[0][7]),\
                   "+v"(a[1][0]), "+v"(a[1][1]), "+v"(a[1][2]), "+v"(a[1][3]),\
                   "+v"(a[1][4]), "+v"(a[1][5]), "+v"(a[1][6]), "+v"(a[1][7]) \
                 :: "memory");                                                \
    __builtin_amdgcn_sched_barrier(0)

// Raw barrier: LDS-safe (lgkm drained) but does NOT drain vmcnt.
#define RAW_BARRIER()                                                         \
    asm volatile("s_waitcnt lgkmcnt(0)\n\ts_barrier" ::: "memory")

// ---------------------------------------------------------------------------
// Persistent recurrence: 128 WGs x 512 thr (8 waves).
// WG = (rh = blk&1 -> 32 batch rows) x (cg = blk>>1 -> 32 cols).
// Wave wid = K-slice [wid*256, +256). Per wave: 16 frags, ONE drain, 32 MFMA.
// Sync redesign vs r13:
//  - arrival flags are PER-EPI-WAVE (flags[blk*4+wid], stored right after the
//    wave's own vmcnt(0) drain; no producer-side WG barrier before flagging)
//  - aggregator (blk 0 / blk 1, wave 7) polls its half's 256 flags with 4
//    PIPELINED asm loads + one drain (not serialized atomic loads)
//  - root flag REPLICATED x16 per half at 64B stride; <=4 consumer WGs poll
//    each copy (kills single-L3-line poll serialization)
// ---------------------------------------------------------------------------
__global__ __launch_bounds__(512, 2) void rnn_persistent(
    const unsigned short* __restrict__ w_bf,   // [2048][2048] bf16
    unsigned short* __restrict__ h_bf,         // [2][64][2048] bf16 ping-pong
    const float* __restrict__ b_hh,            // [2048]
    const float* __restrict__ internal,        // [64][512]
    float* __restrict__ out,                   // [B][T][H] ++ [B][H]
    unsigned int* __restrict__ flags)          // [512] arrivals + [512] roots
{
    __shared__ f32x4 red4[8 * 256];            // 32 KiB

    const int tid  = threadIdx.x;
    const int lane = tid & 63;
    const int wid  = tid >> 6;                 // K-slice 0..7
    const int rlo  = lane & 15;
    const int khi  = lane >> 4;
    const int blk  = blockIdx.x;
    const int rh   = blk & 1;                  // rows rh*32..+31
    const int cg   = blk >> 1;                 // cols cg*32..+31

    // ---- preload w_hh slice (register/AGPR-resident across all steps)
    bf16x8 wf[2][8];
    {
        const unsigned short* w0 =
            w_bf + (size_t)(cg * 32 + rlo) * Hh + wid * 256 + khi * 8;
        const unsigned short* w1 = w0 + (size_t)16 * Hh;
        LD_FRAG_C(wf[0][0], w0, "0");   LD_FRAG_C(wf[0][1], w0, "64");
        LD_FRAG_C(wf[0][2], w0, "128"); LD_FRAG_C(wf[0][3], w0, "192");
        LD_FRAG_C(wf[0][4], w0, "256"); LD_FRAG_C(wf[0][5], w0, "320");
        LD_FRAG_C(wf[0][6], w0, "384"); LD_FRAG_C(wf[0][7], w0, "448");
        LD_FRAG_C(wf[1][0], w1, "0");   LD_FRAG_C(wf[1][1], w1, "64");
        LD_FRAG_C(wf[1][2], w1, "128"); LD_FRAG_C(wf[1][3], w1, "192");
        LD_FRAG_C(wf[1][4], w1, "256"); LD_FRAG_C(wf[1][5], w1, "320");
        LD_FRAG_C(wf[1][6], w1, "384"); LD_FRAG_C(wf[1][7], w1, "448");
        DRAIN16(wf);
    }

    // ---- epilogue decode (r9/r10/r13 verified)
    const int em    = (tid >> 6) & 1;
    const int ent   = (tid >> 7) & 1;          // valid for tid<256
    const int odd   = lane & 1;
    const int clloc = (ent * 16 + rlo) & ~1;
    const int cl    = cg * 32 + clloc;         // even col of the pair
    const int rAl   = em * 16 + khi * 4 + 2 * odd;
    const int rAg   = rh * 32 + rAl;           // global batch row A
    const int rBg   = rAg + 1;                 // global batch row B
    const float2 bh2 = (tid < 256) ? *(const float2*)(b_hh + cl)
                                   : make_float2(0.f, 0.f);

    float2 xpA = make_float2(0.f, 0.f), xpB = make_float2(0.f, 0.f);
    float  nzA = 0.f, nzB = 0.f;
    if (tid < 256) {
        xpA = *(const float2*)(out + ((size_t)rAg * Tt + 0) * Hh + cl);
        xpB = *(const float2*)(out + ((size_t)rBg * Tt + 0) * Hh + cl);
        nzA = internal[rAg * Tt + 0];
        nzB = internal[rBg * Tt + 0];
    }
    float2 gA_d = make_float2(0.f, 0.f), gB_d = make_float2(0.f, 0.f);

    // sync addresses
    unsigned int* myflag   = flags + blk * 4 + wid;          // epi waves only
    unsigned int* aggbase  = flags + 8 * lane + 4 * rh;      // aggregator scan
    unsigned int* rootst   = flags + 512 + (rh * 16 + lane) * 16;   // agg store
    unsigned int* rootpoll = flags + 512 + (rh * 16 + ((blk >> 1) & 15)) * 16;

    for (int t = 0; t < Tt; ++t) {
        const bool last = (t == Tt - 1);
        const unsigned short* h_cur = h_bf + (size_t)(t & 1) * Bb * Hh;
        unsigned short*       h_nxt = h_bf + (size_t)((t + 1) & 1) * Bb * Hh;

        // ---- (a) issue h-fragment loads first (longest latency)
        const unsigned short* am0 =
            h_cur + (size_t)(rh * 32 + rlo) * Hh + wid * 256 + khi * 8;
        const unsigned short* am1 = am0 + (size_t)16 * Hh;

        bf16x8 a[2][8];
        LD_FRAG(a[0][0], am0, "0");   LD_FRAG(a[0][1], am0, "64");
        LD_FRAG(a[0][2], am0, "128"); LD_FRAG(a[0][3], am0, "192");
        LD_FRAG(a[0][4], am0, "256"); LD_FRAG(a[0][5], am0, "320");
        LD_FRAG(a[0][6], am0, "384"); LD_FRAG(a[0][7], am0, "448");
        LD_FRAG(a[1][0], am1, "0");   LD_FRAG(a[1][1], am1, "64");
        LD_FRAG(a[1][2], am1, "128"); LD_FRAG(a[1][3], am1, "192");
        LD_FRAG(a[1][4], am1, "256"); LD_FRAG(a[1][5], am1, "320");
        LD_FRAG(a[1][6], am1, "384"); LD_FRAG(a[1][7], am1, "448");

        // ---- (b) deferred out[t-1] stores ride the same drain
        if (tid < 256 && t > 0) {
            *(float2*)(out + ((size_t)rAg * Tt + (t - 1)) * Hh + cl) = gA_d;
            *(float2*)(out + ((size_t)rBg * Tt + (t - 1)) * Hh + cl) = gB_d;
        }

        // ---- (d) single drain releases everything (incl. xp prefetches)
        DRAIN16(a);

        // ---- (e) MFMA: 2 mtiles x 2 ntiles x 8 kits
        f32x4 acc[2][2];
        #pragma unroll
        for (int m = 0; m < 2; ++m)
            #pragma unroll
            for (int nt = 0; nt < 2; ++nt) acc[m][nt] = (f32x4)0.f;
        #pragma unroll
        for (int kk = 0; kk < 8; ++kk)
            #pragma unroll
            for (int m = 0; m < 2; ++m)
                #pragma unroll
                for (int nt = 0; nt < 2; ++nt)
                    acc[m][nt] = __builtin_amdgcn_mfma_f32_16x16x32_bf16(
                        a[m][kk], wf[nt][kk], acc[m][nt], 0, 0, 0);

        // ---- (f) 8-way k-split reduce (raw barrier: LDS only)
        #pragma unroll
        for (int nt = 0; nt < 2; ++nt)
            #pragma unroll
            for (int m = 0; m < 2; ++m)
                red4[wid * 256 + (nt * 2 + m) * 64 + lane] = acc[m][nt];
        RAW_BARRIER();

        // ---- (g) epilogue: waves 0-3; each wave flags independently
        if (tid < 256) {
            f32x4 s4 = (f32x4)0.f;
            #pragma unroll
            for (int ks = 0; ks < 8; ++ks)
                s4 += red4[ks * 256 + tid];

            f32x4 o4;
            #pragma unroll
            for (int i = 0; i < 4; ++i)
                o4[i] = __shfl_xor(s4[i], 1, 64);

            const float sA_lo = odd ? o4[2] : s4[0];
            const float sA_hi = odd ? s4[2] : o4[0];
            const float sB_lo = odd ? o4[3] : s4[1];
            const float sB_hi = odd ? s4[3] : o4[1];

            float2 gA, gB;
            gA.x = tanhf(xpA.x + nzA + bh2.x + sA_lo);
            gA.y = tanhf(xpA.y + nzA + bh2.y + sA_hi);
            gB.x = tanhf(xpB.x + nzB + bh2.x + sB_lo);
            gB.y = tanhf(xpB.y + nzB + bh2.y + sB_hi);

            const unsigned int hpA =
                (unsigned int)f2bf(gA.x) | ((unsigned int)f2bf(gA.y) << 16);
            const unsigned int hpB =
                (unsigned int)f2bf(gB.x) | ((unsigned int)f2bf(gB.y) << 16);
            __hip_atomic_store((unsigned int*)h_nxt + ((size_t)rAg * Hh + cl) / 2,
                               hpA, __ATOMIC_RELAXED, __HIP_MEMORY_SCOPE_AGENT);
            __hip_atomic_store((unsigned int*)h_nxt + ((size_t)rBg * Hh + cl) / 2,
                               hpB, __ATOMIC_RELAXED, __HIP_MEMORY_SCOPE_AGENT);

            if (last) {
                *(float2*)(out + ((size_t)rAg * Tt + t) * Hh + cl) = gA;
                *(float2*)(out + ((size_t)rBg * Tt + t) * Hh + cl) = gB;
                float* tail = out + (size_t)Bb * Tt * Hh;
                *(float2*)(tail + (size_t)rAg * Hh + cl) = gA;
                *(float2*)(tail + (size_t)rBg * Hh + cl) = gB;
            } else {
                gA_d = gA; gB_d = gB;      // defer to next iteration

                // per-WAVE drain of own h stores, then own arrival flag
                asm volatile("s_waitcnt vmcnt(0)" ::: "memory");
                if (lane == 0)
                    __hip_atomic_store(myflag, (unsigned int)(t + 1),
                                       __ATOMIC_RELAXED,
                                       __HIP_MEMORY_SCOPE_AGENT);

                // xp/nz prefetch for t+1 rides the poll; drained by DRAIN16
                xpA = *(const float2*)(out + ((size_t)rAg * Tt + t + 1) * Hh + cl);
                xpB = *(const float2*)(out + ((size_t)rBg * Tt + t + 1) * Hh + cl);
                nzA = internal[rAg * Tt + t + 1];
                nzB = internal[rBg * Tt + t + 1];
            }
        }
        if (last) break;

        // ---- tree barrier: aggregator per half + replicated roots
        const unsigned int tgt = (unsigned int)(t + 1);
        if (blk < 2 && wid == 7) {
            // aggregator for half `blk`: 256 flags via 4 pipelined asm loads
            unsigned int f0, f1, f2, f3;
            while (true) {
                asm volatile("global_load_dword %0, %1, off sc0 sc1"
                             : "=v"(f0) : "v"(aggbase));
                asm volatile("global_load_dword %0, %1, off offset:4 sc0 sc1"
                             : "=v"(f1) : "v"(aggbase));
                asm volatile("global_load_dword %0, %1, off offset:8 sc0 sc1"
                             : "=v"(f2) : "v"(aggbase));
                asm volatile("global_load_dword %0, %1, off offset:12 sc0 sc1"
                             : "=v"(f3) : "v"(aggbase));
                asm volatile("s_waitcnt vmcnt(0)"
                             : "+v"(f0), "+v"(f1), "+v"(f2), "+v"(f3)
                             :: "memory");
                if (__all(f0 >= tgt && f1 >= tgt && f2 >= tgt && f3 >= tgt))
                    break;
                __builtin_amdgcn_s_sleep(1);
            }
            if (lane < 16)
                __hip_atomic_store(rootst, tgt, __ATOMIC_RELAXED,
                                   __HIP_MEMORY_SCOPE_AGENT);
        } else if (wid == 7) {
            // consumers: poll this WG's root copy (<=4 WGs per copy)
            while (__hip_atomic_load(rootpoll, __ATOMIC_RELAXED,
                                     __HIP_MEMORY_SCOPE_AGENT) < tgt)
                __builtin_amdgcn_s_sleep(1);
        }
        RAW_BARRIER();                     // release: root seen by wave 7
    }
}

// ---------------------------------------------------------------------------
extern "C" void kernel_launch(void* const* d_in, const int* in_sizes, int n_in,
                              void* d_out, int out_size, void* d_ws, size_t ws_size,
                              hipStream_t stream) {
    const float* input    = (const float*)d_in[0];
    const float* internal = (const float*)d_in[1];
    const float* w_ih     = (const float*)d_in[2];
    const float* w_hh     = (const float*)d_in[3];
    const float* b_ih     = (const float*)d_in[4];
    const float* b_hh     = (const float*)d_in[5];
    const float* h0       = (const float*)d_in[6];
    float* out = (float*)d_out;

    // ws: w_hh_bf [4M us] | w_ih_bf [2M us] | h_bf[2][64][2048] | flags[1024]
    unsigned short* w_hh_bf = (unsigned short*)d_ws;
    unsigned short* w_ih_bf = w_hh_bf + (size_t)Hh * Hh;
    unsigned short* h_bf    = w_ih_bf + (size_t)Hh * Ii;
    unsigned int*   flags   = (unsigned int*)(h_bf + (size_t)2 * Bb * Hh);

    hipLaunchKernelGGL(init_flags, dim3(1), dim3(1024), 0, stream, flags);
    hipLaunchKernelGGL(cvt_kernel, dim3((Hh * Hh) / 1024), dim3(256), 0, stream,
                       w_hh, w_hh_bf);
    hipLaunchKernelGGL(cvt_kernel, dim3((Hh * Ii) / 1024), dim3(256), 0, stream,
                       w_ih, w_ih_bf);
    hipLaunchKernelGGL(cvt_kernel, dim3((Bb * Hh) / 1024), dim3(256), 0, stream,
                       h0, h_bf);

    dim3 g1(Hh / 128, (Bb * Tt) / 128);
    hipLaunchKernelGGL(xproj_kernel, g1, dim3(256), 0, stream,
                       input, w_ih_bf, b_ih, out);

    void* args[] = {(void*)&w_hh_bf, (void*)&h_bf, (void*)&b_hh,
                    (void*)&internal, (void*)&out, (void*)&flags};
    hipLaunchCooperativeKernel((void*)rnn_persistent, dim3(NBLK), dim3(512),
                               args, 0, stream);
}